// Round 5
// baseline (534.232 us; speedup 1.0000x reference)
//
#include <hip/hip_runtime.h>

#define D 256
#define SB 1024
typedef __attribute__((ext_vector_type(8))) short short8;
typedef __attribute__((ext_vector_type(4))) float floatx4;

__device__ __forceinline__ unsigned short f2bf(float f) {
  unsigned int u = __float_as_uint(f);
  u = (u + 0x7FFF + ((u >> 16) & 1)) >> 16;   // RNE
  return (unsigned short)u;
}
__device__ __forceinline__ float bf2f(unsigned short h) {
  return __uint_as_float(((unsigned int)h) << 16);
}

// async global->LDS, 16B per lane; LDS dest = wave-uniform base + lane*16
__device__ __forceinline__ void glds16(const void* g, void* l) {
  __builtin_amdgcn_global_load_lds(
      (const __attribute__((address_space(1))) unsigned int*)g,
      (__attribute__((address_space(3))) unsigned int*)l, 16, 0, 0);
}

// ---------------- fused independent setup: zero | bounds | cvt | cvt_w x2 --
__global__ __launch_bounds__(256) void k_setup(
    int* __restrict__ cur, int RN,
    const int* __restrict__ batch, int* __restrict__ gstart, int N, int G,
    const float* __restrict__ table, unsigned short* __restrict__ tableb, int TN,
    const float* __restrict__ root1, const float* __restrict__ W1,
    const float* __restrict__ root2, const float* __restrict__ W2,
    unsigned short* __restrict__ wb,
    int g0, int g1, int g2, int g3) {
  int b = blockIdx.x, t = threadIdx.x;
  if (b < g0) {                       // zero cur, int4 per thread
    int i = b * 1024 + t * 4;
#pragma unroll
    for (int j = 0; j < 4; j++) if (i + j < RN) cur[i + j] = 0;
  } else if (b < g1) {                // graph bounds
    int i = (b - g0) * 256 + t;
    if (i >= N) return;
    int bb = batch[i];
    if (i == 0) { for (int g = 0; g <= bb; g++) gstart[g] = 0; }
    else { int pb = batch[i - 1]; for (int g = pb + 1; g <= bb; g++) gstart[g] = i; }
    if (i == N - 1) { for (int g = bb + 1; g <= G; g++) gstart[g] = N; }
  } else if (b < g2) {                // table fp32 -> bf16
    int i = (b - g1) * 256 + t;
    if (i < TN) tableb[i] = f2bf(table[i]);
  } else {                            // weights -> bf16 transposed [mat][n][k]
    int layer = (b < g3) ? 0 : 1;
    int idx = ((b - (layer ? g3 : g2)) * 256 + t);   // 0 .. 4*65536-1
    int mat = idx >> 16, rem = idx & 65535;
    int n = rem >> 8, k = rem & 255;
    const float* root = layer ? root2 : root1;
    const float* W = layer ? W2 : W1;
    const float* s = (mat == 0) ? root : (W + (size_t)(mat - 1) * 65536);
    wb[(size_t)layer * 4 * 65536 + idx] = f2bf(s[k * 256 + n]);
  }
}

// ---------------- per-(relation,node) in-edge counts ----------------
__global__ __launch_bounds__(256) void k_count_i(const int* __restrict__ dst,
    const int* __restrict__ et, int* __restrict__ cnt, int E, int N) {
  int e = blockIdx.x * 256 + threadIdx.x;
  if (e >= E) return;
  atomicAdd(&cnt[et[e] * N + dst[e]], 1);
}

// ---------------- 3-kernel scan chain (proven r11/r14) ----------------
__global__ __launch_bounds__(256) void k_scan1(const int* __restrict__ in,
    int* __restrict__ bsum, int n) {
  __shared__ int s[256];
  int base = blockIdx.x * SB, t = threadIdx.x;
  int a = 0;
#pragma unroll
  for (int j = 0; j < 4; j++) { int i = base + t * 4 + j; if (i < n) a += in[i]; }
  s[t] = a; __syncthreads();
  for (int o = 128; o > 0; o >>= 1) { if (t < o) s[t] += s[t + o]; __syncthreads(); }
  if (t == 0) bsum[blockIdx.x] = s[0];
}

__global__ __launch_bounds__(256) void k_scan2(int* __restrict__ bsum, int nb,
    int* __restrict__ total_out) {
  __shared__ int s[256];
  int t = threadIdx.x;
  int v[4]; int a = 0;
#pragma unroll
  for (int j = 0; j < 4; j++) {
    int i = t * 4 + j;
    v[j] = (i < nb) ? bsum[i] : 0;
    a += v[j];
  }
  s[t] = a; __syncthreads();
  for (int o = 1; o < 256; o <<= 1) {
    int x_ = (t >= o) ? s[t - o] : 0;
    __syncthreads();
    s[t] += x_;
    __syncthreads();
  }
  int excl = (t > 0) ? s[t - 1] : 0;
#pragma unroll
  for (int j = 0; j < 4; j++) {
    int i = t * 4 + j;
    if (i < nb) { bsum[i] = excl; excl += v[j]; }
  }
  if (t == 255) *total_out = s[255];
}

__global__ __launch_bounds__(256) void k_scan3(const int* __restrict__ in,
    const int* __restrict__ bsum, int* __restrict__ off, int* __restrict__ cur,
    int n) {
  __shared__ int s[256];
  int base = blockIdx.x * SB, t = threadIdx.x;
  int v[4]; int a = 0;
#pragma unroll
  for (int j = 0; j < 4; j++) {
    int i = base + t * 4 + j;
    v[j] = (i < n) ? in[i] : 0;
    a += v[j];
  }
  s[t] = a; __syncthreads();
  for (int o = 1; o < 256; o <<= 1) {
    int x_ = (t >= o) ? s[t - o] : 0;
    __syncthreads();
    s[t] += x_;
    __syncthreads();
  }
  int excl = (t > 0 ? s[t - 1] : 0) + bsum[blockIdx.x];
#pragma unroll
  for (int j = 0; j < 4; j++) {
    int i = base + t * 4 + j;
    if (i < n) { off[i] = excl; cur[i] = excl; excl += v[j]; }
  }
}

// CSR placement: esx[pos] = x[src] (L1 row id), ess[pos] = src (L2 row id)
__global__ __launch_bounds__(256) void k_place2(const int* __restrict__ src,
    const int* __restrict__ dst, const int* __restrict__ et,
    const int* __restrict__ x, int* __restrict__ cur,
    int* __restrict__ esx, int* __restrict__ ess, int E, int N) {
  int e = blockIdx.x * 256 + threadIdx.x;
  if (e >= E) return;
  int s = src[e];
  int pos = atomicAdd(&cur[et[e] * N + dst[e]], 1);
  esx[pos] = x[s];
  ess[pos] = s;
}

// ---------------- fused K=1024 bf16 MFMA GEMM + on-the-fly relation agg ---
// r22: r0's schedule (best: 86us, 3 blocks/CU — occupancy beats every hand
// pipeline tried in r18-r21) + AGGREGATION FUSED INTO A-STAGING. Previously
// k_agg wrote 153.6 MB/layer of mean-aggregated rows to HBM and k_lgemm
// re-read them as A segs 1-3. Now: for steps in segs 1-3, gather the CSR
// source rows directly from the L3-resident feature table (tableb 5MB /
// P0 51MB), fp32-accumulate, mean, ds_write bf16 into the A-tile. Math is
// bit-identical to k_agg (same fp32 accum + RNE f2bf). Both k_agg launches
// and the agg round-trip traffic are eliminated. Step structure unchanged
// from r0: {sync; stage (glds B, glds A seg0 | gather segs1-3); sync;
// compute} — the second __syncthreads drains vmcnt AND lgkmcnt, covering
// both glds and ds_write visibility. 4-elem accumulators keep VGPR near
// r0's 56 (a0base[4] ptr array deleted) to preserve 3 blocks/CU.
__global__ __launch_bounds__(512) void k_lgemm(
    const unsigned short* __restrict__ Aroot, const int* __restrict__ gidx,
    const int* __restrict__ rows_, const int* __restrict__ off_,
    const unsigned short* __restrict__ wb,
    const float* __restrict__ bias, unsigned short* Cout, int M, int N) {
  __shared__ unsigned short AsU[2][128 * 32];    // 2 x 8 KB  [row][k]
  __shared__ unsigned short BsU[2][256 * 32];    // 2 x 16 KB [n][k]
  __shared__ int   csr_lo[3][128];
  __shared__ int   csr_hi[3][128];
  __shared__ float csr_inv[3][128];
  const int tid = threadIdx.x;
  const int w = tid >> 6, lane = tid & 63;
  const int wr = w >> 2, wc = w & 3;             // wave grid 2x4
  const int i0 = blockIdx.x * 128;
  const int ml = lane & 15, q = lane >> 4;

  // CSR metadata for this block's 128 rows x 3 relations
  if (tid < 384) {
    int rel = tid >> 7, rl = tid & 127;
    int r = i0 + rl;
    int gid = rel * N + ((r < M) ? r : (M - 1));
    int lo = off_[gid];
    int hi = (r < M) ? off_[gid + 1] : lo;
    csr_lo[rel][rl] = lo;
    csr_hi[rel][rl] = hi;
    int c = hi - lo;
    csr_inv[rel][rl] = 1.0f / (float)(c > 0 ? c : 1);
  }

  // A seg0 staging: wave w stages rows w*16..w*16+15 (1 KB / instr).
  const int arow = w * 16 + (lane >> 2);         // row in [0,128)
  const int achunk = lane & 3;                   // 8-short chunk in 32-half
  int ra = i0 + arow;
  int rac = (ra < M) ? ra : (M - 1);
  const int rowA0 = gidx ? gidx[rac] : rac;
  const unsigned short* a0base = Aroot + (size_t)rowA0 * D + achunk * 8;

  // B staging: wave w stages rows w*32..w*32+31 (2 instrs of 1 KB).
  const int brow = w * 32 + (lane >> 2);
  const int bchunk = lane & 3;
  const size_t bofs = (size_t)brow * D + bchunk * 8;

  floatx4 acc[4][4];
#pragma unroll
  for (int i = 0; i < 4; i++)
#pragma unroll
    for (int j = 0; j < 4; j++) acc[i][j] = (floatx4){0.f, 0.f, 0.f, 0.f};

  unsigned short* aldst[2] = {&AsU[0][w * 512], &AsU[1][w * 512]};
  unsigned short* bldst0[2] = {&BsU[0][w * 1024], &BsU[1][w * 1024]};
  unsigned short* bldst1[2] = {&BsU[0][w * 1024 + 512], &BsU[1][w * 1024 + 512]};

  for (int step = 0; step < 16; ++step) {
    const int seg = step >> 2;          // K-segment: 0=root, 1..3=relations
    __syncthreads();                    // previous step's LDS reads done
#pragma unroll
    for (int h = 0; h < 2; h++) {
      const int kloc = (step * 64 + h * 32) & 255;
      if (seg == 0) glds16(a0base + kloc, aldst[h]);
      const unsigned short* bb = wb + (size_t)seg * 65536 + bofs + kloc;
      glds16(bb, bldst0[h]);
      glds16(bb + 16 * D, bldst1[h]);
    }
    if (seg > 0) {
      // on-the-fly mean-aggregation of this step's A-tile slice
      const int rel = seg - 1;
      const int lo = csr_lo[rel][arow], hi = csr_hi[rel][arow];
      const float inv = csr_inv[rel][arow];
#pragma unroll
      for (int h = 0; h < 2; h++) {
        const int kloc = (step * 64 + h * 32) & 255;
        const unsigned short* gsrc = Aroot + kloc + achunk * 8;
#pragma unroll
        for (int sub = 0; sub < 2; ++sub) {
          float a0 = 0.f, a1 = 0.f, a2 = 0.f, a3 = 0.f;
          for (int p = lo; p < hi; ++p) {
            int rid = rows_[p];
            ushort4 v = *(const ushort4*)(gsrc + (size_t)rid * D + sub * 4);
            a0 += bf2f(v.x); a1 += bf2f(v.y);
            a2 += bf2f(v.z); a3 += bf2f(v.w);
          }
          ushort4 o;
          o.x = f2bf(a0 * inv); o.y = f2bf(a1 * inv);
          o.z = f2bf(a2 * inv); o.w = f2bf(a3 * inv);
          *(ushort4*)&AsU[h][w * 512 + lane * 8 + sub * 4] = o;
        }
      }
    }
    __syncthreads();                    // vmcnt+lgkmcnt drained -> LDS ready

#pragma unroll
    for (int h = 0; h < 2; h++) {
      short8 aF[4], bF[4];
#pragma unroll
      for (int mi = 0; mi < 4; mi++)
        aF[mi] = *(const short8*)&AsU[h][(wr * 64 + mi * 16 + ml) * 32 + q * 8];
#pragma unroll
      for (int ni = 0; ni < 4; ni++)
        bF[ni] = *(const short8*)&BsU[h][(wc * 64 + ni * 16 + ml) * 32 + q * 8];
#pragma unroll
      for (int mi = 0; mi < 4; mi++)
#pragma unroll
        for (int ni = 0; ni < 4; ni++)
          acc[mi][ni] = __builtin_amdgcn_mfma_f32_16x16x32_bf16(
              aF[mi], bF[ni], acc[mi][ni], 0, 0, 0);
    }
  }

  // per-block read-before-write over input pages: reads precede C writes
  __syncthreads();

  // epilogue: bias + ReLU + bf16; C/D layout col=lane&15, row=q*4+reg
  float bv[4];
#pragma unroll
  for (int ni = 0; ni < 4; ni++) bv[ni] = bias[wc * 64 + ni * 16 + ml];
#pragma unroll
  for (int mi = 0; mi < 4; mi++) {
#pragma unroll
    for (int ni = 0; ni < 4; ni++) {
      int col = wc * 64 + ni * 16 + ml;
#pragma unroll
      for (int j = 0; j < 4; j++) {
        int row = i0 + wr * 64 + mi * 16 + q * 4 + j;
        if (row < M) {
          float v = fmaxf(acc[mi][ni][j] + bv[ni], 0.f);
          Cout[(size_t)row * D + col] = f2bf(v);
        }
      }
    }
  }
}

// ---------------- fused graph mean-pool + linear head ----------------
__global__ __launch_bounds__(256) void k_poolfinal(
    const unsigned short* __restrict__ h, const int* __restrict__ gstart,
    const float* __restrict__ linW, const float* __restrict__ linb,
    float* __restrict__ out, int G) {
  __shared__ float red[4][D];
  __shared__ float sred[4][4];
  int g = blockIdx.x;
  int lo = gstart[g], hi = gstart[g + 1];
  int tid = threadIdx.x, wave = tid >> 6, lane = tid & 63;
  float a0 = 0.f, a1 = 0.f, a2 = 0.f, a3 = 0.f;
  for (int i = lo + wave; i < hi; i += 4) {
    ushort4 v = *(const ushort4*)(h + (size_t)i * D + lane * 4);
    a0 += bf2f(v.x); a1 += bf2f(v.y); a2 += bf2f(v.z); a3 += bf2f(v.w);
  }
  red[wave][lane * 4 + 0] = a0;
  red[wave][lane * 4 + 1] = a1;
  red[wave][lane * 4 + 2] = a2;
  red[wave][lane * 4 + 3] = a3;
  __syncthreads();
  float s = red[0][tid] + red[1][tid] + red[2][tid] + red[3][tid];
  float inv = (hi > lo) ? 1.0f / (float)(hi - lo) : 0.0f;
  float m = s * inv;                       // mean feature tid
  float4 wrow = *(const float4*)(linW + tid * 4);
  float p0 = m * wrow.x, p1 = m * wrow.y, p2 = m * wrow.z, p3 = m * wrow.w;
  for (int o = 32; o > 0; o >>= 1) {
    p0 += __shfl_down(p0, o, 64);
    p1 += __shfl_down(p1, o, 64);
    p2 += __shfl_down(p2, o, 64);
    p3 += __shfl_down(p3, o, 64);
  }
  if (lane == 0) {
    sred[wave][0] = p0; sred[wave][1] = p1;
    sred[wave][2] = p2; sred[wave][3] = p3;
  }
  __syncthreads();
  if (tid < 4)
    out[g * 4 + tid] = sred[0][tid] + sred[1][tid] + sred[2][tid] +
                       sred[3][tid] + linb[tid];
}

extern "C" void kernel_launch(void* const* d_in, const int* in_sizes, int n_in,
                              void* d_out, int out_size, void* d_ws, size_t ws_size,
                              hipStream_t stream) {
  const int*   x     = (const int*)d_in[0];
  const int*   ei    = (const int*)d_in[1];
  const int*   et    = (const int*)d_in[2];
  const int*   batch = (const int*)d_in[3];
  const float* table = (const float*)d_in[5];
  const float* W1    = (const float*)d_in[6];
  const float* root1 = (const float*)d_in[7];
  const float* b1    = (const float*)d_in[8];
  const float* W2    = (const float*)d_in[9];
  const float* root2 = (const float*)d_in[10];
  const float* b2    = (const float*)d_in[11];
  const float* linW  = (const float*)d_in[12];
  const float* linb  = (const float*)d_in[13];
  float* out = (float*)d_out;

  const int N = in_sizes[0];
  const int E = in_sizes[2];
  const int G = out_size / 4;
  const int VOC = in_sizes[5] / D;
  const int* src = ei;
  const int* dst = ei + E;
  const int RN = 3 * N;

  // ---- ws layout, page aliasing proven rounds 5-17 ----
  char* wsb = (char*)d_ws;
  size_t pg = (size_t)N * D * 2;
  unsigned short* P0 = (unsigned short*)wsb;             // L1 output
  unsigned short* P1 = (unsigned short*)(wsb + pg);      // L2 output
  unsigned short* P3 = (unsigned short*)(wsb + 3 * pg);
  unsigned short* wb = (unsigned short*)(wsb + 4 * pg);  // 2 layers x 4 mats
  int*   off    = (int*)(wb + 2 * 4 * 65536);
  int*   esx    = off + (RN + 1);       // L1 row ids (= x[src])
  int*   ess    = esx + E;              // L2 row ids (= src)
  int*   gstart = ess + E;
  unsigned short* tableb = P3;          // alias (never overwritten now)
  int* cur  = (int*)P0;                 // alias (dead before L1 GEMM writes P0)
  int* bsum = cur + RN;                 // alias

  const int nb = (RN + SB - 1) / SB;

  // ---- setup: one fused kernel for all independent prep ----
  int nbZero = (RN + 1023) / 1024;
  int nbBounds = (N + 255) / 256;
  int nbCvt = (VOC * D + 255) / 256;
  int g0 = nbZero, g1 = g0 + nbBounds, g2 = g1 + nbCvt, g3 = g2 + 1024;
  k_setup<<<g3 + 1024, 256, 0, stream>>>(cur, RN, batch, gstart, N, G,
      table, tableb, VOC * D, root1, W1, root2, W2, wb, g0, g1, g2, g3);

  k_count_i<<<(E + 255) / 256, 256, 0, stream>>>(dst, et, cur, E, N);
  k_scan1<<<nb, 256, 0, stream>>>(cur, bsum, RN);
  k_scan2<<<1, 256, 0, stream>>>(bsum, nb, off + RN);
  k_scan3<<<nb, 256, 0, stream>>>(cur, bsum, off, cur, RN);
  k_place2<<<(E + 255) / 256, 256, 0, stream>>>(src, dst, et, x, cur, esx, ess, E, N);

  const int ggemm = (N + 127) / 128;

  // ---- layer 1: fused agg+GEMM (gathers tableb rows via esx) ----
  k_lgemm<<<ggemm, 512, 0, stream>>>(tableb, x, esx, off, wb, b1, P0, N, N);
  // ---- layer 2: fused agg+GEMM (gathers P0 rows via ess) ----
  k_lgemm<<<ggemm, 512, 0, stream>>>(P0, nullptr, ess, off, wb + 4 * 65536, b2, P1, N, N);

  // ---- pool + head fused ----
  k_poolfinal<<<G, 256, 0, stream>>>(P1, gstart, linW, linb, out, G);
}

// Round 6
// 380.700 us; speedup vs baseline: 1.4033x; 1.4033x over previous
//
#include <hip/hip_runtime.h>

#define D 256
#define SB 1024
typedef __attribute__((ext_vector_type(8))) short short8;
typedef __attribute__((ext_vector_type(4))) float floatx4;

__device__ __forceinline__ unsigned short f2bf(float f) {
  unsigned int u = __float_as_uint(f);
  u = (u + 0x7FFF + ((u >> 16) & 1)) >> 16;   // RNE
  return (unsigned short)u;
}
__device__ __forceinline__ float bf2f(unsigned short h) {
  return __uint_as_float(((unsigned int)h) << 16);
}

// async global->LDS, 16B per lane; LDS dest = wave-uniform base + lane*16
__device__ __forceinline__ void glds16(const void* g, void* l) {
  __builtin_amdgcn_global_load_lds(
      (const __attribute__((address_space(1))) unsigned int*)g,
      (__attribute__((address_space(3))) unsigned int*)l, 16, 0, 0);
}

// ---------------- fused independent setup: zero | bounds | cvt | cvt_w x2 --
__global__ __launch_bounds__(256) void k_setup(
    int* __restrict__ cur, int RN,
    const int* __restrict__ batch, int* __restrict__ gstart, int N, int G,
    const float* __restrict__ table, unsigned short* __restrict__ tableb, int TN,
    const float* __restrict__ root1, const float* __restrict__ W1,
    const float* __restrict__ root2, const float* __restrict__ W2,
    unsigned short* __restrict__ wb, int* __restrict__ zrowi,
    int g0, int g1, int g2, int g3) {
  int b = blockIdx.x, t = threadIdx.x;
  if (b < g0) {                       // zero cur, int4 per thread
    int i = b * 1024 + t * 4;
#pragma unroll
    for (int j = 0; j < 4; j++) if (i + j < RN) cur[i + j] = 0;
    if (b == 0 && t < 128) zrowi[t] = 0;   // 512B zero feature row
  } else if (b < g1) {                // graph bounds
    int i = (b - g0) * 256 + t;
    if (i >= N) return;
    int bb = batch[i];
    if (i == 0) { for (int g = 0; g <= bb; g++) gstart[g] = 0; }
    else { int pb = batch[i - 1]; for (int g = pb + 1; g <= bb; g++) gstart[g] = i; }
    if (i == N - 1) { for (int g = bb + 1; g <= G; g++) gstart[g] = N; }
  } else if (b < g2) {                // table fp32 -> bf16
    int i = (b - g1) * 256 + t;
    if (i < TN) tableb[i] = f2bf(table[i]);
  } else {                            // weights -> bf16 transposed [mat][n][k]
    int layer = (b < g3) ? 0 : 1;
    int idx = ((b - (layer ? g3 : g2)) * 256 + t);   // 0 .. 4*65536-1
    int mat = idx >> 16, rem = idx & 65535;
    int n = rem >> 8, k = rem & 255;
    const float* root = layer ? root2 : root1;
    const float* W = layer ? W2 : W1;
    const float* s = (mat == 0) ? root : (W + (size_t)(mat - 1) * 65536);
    wb[(size_t)layer * 4 * 65536 + idx] = f2bf(s[k * 256 + n]);
  }
}

// ---------------- per-(relation,node) in-edge counts ----------------
__global__ __launch_bounds__(256) void k_count_i(const int* __restrict__ dst,
    const int* __restrict__ et, int* __restrict__ cnt, int E, int N) {
  int e = blockIdx.x * 256 + threadIdx.x;
  if (e >= E) return;
  atomicAdd(&cnt[et[e] * N + dst[e]], 1);
}

// ---------------- 3-kernel scan chain (proven r11/r14) ----------------
__global__ __launch_bounds__(256) void k_scan1(const int* __restrict__ in,
    int* __restrict__ bsum, int n) {
  __shared__ int s[256];
  int base = blockIdx.x * SB, t = threadIdx.x;
  int a = 0;
#pragma unroll
  for (int j = 0; j < 4; j++) { int i = base + t * 4 + j; if (i < n) a += in[i]; }
  s[t] = a; __syncthreads();
  for (int o = 128; o > 0; o >>= 1) { if (t < o) s[t] += s[t + o]; __syncthreads(); }
  if (t == 0) bsum[blockIdx.x] = s[0];
}

__global__ __launch_bounds__(256) void k_scan2(int* __restrict__ bsum, int nb,
    int* __restrict__ total_out) {
  __shared__ int s[256];
  int t = threadIdx.x;
  int v[4]; int a = 0;
#pragma unroll
  for (int j = 0; j < 4; j++) {
    int i = t * 4 + j;
    v[j] = (i < nb) ? bsum[i] : 0;
    a += v[j];
  }
  s[t] = a; __syncthreads();
  for (int o = 1; o < 256; o <<= 1) {
    int x_ = (t >= o) ? s[t - o] : 0;
    __syncthreads();
    s[t] += x_;
    __syncthreads();
  }
  int excl = (t > 0) ? s[t - 1] : 0;
#pragma unroll
  for (int j = 0; j < 4; j++) {
    int i = t * 4 + j;
    if (i < nb) { bsum[i] = excl; excl += v[j]; }
  }
  if (t == 255) *total_out = s[255];
}

__global__ __launch_bounds__(256) void k_scan3(const int* __restrict__ in,
    const int* __restrict__ bsum, int* __restrict__ off, int* __restrict__ cur,
    int n) {
  __shared__ int s[256];
  int base = blockIdx.x * SB, t = threadIdx.x;
  int v[4]; int a = 0;
#pragma unroll
  for (int j = 0; j < 4; j++) {
    int i = base + t * 4 + j;
    v[j] = (i < n) ? in[i] : 0;
    a += v[j];
  }
  s[t] = a; __syncthreads();
  for (int o = 1; o < 256; o <<= 1) {
    int x_ = (t >= o) ? s[t - o] : 0;
    __syncthreads();
    s[t] += x_;
    __syncthreads();
  }
  int excl = (t > 0 ? s[t - 1] : 0) + bsum[blockIdx.x];
#pragma unroll
  for (int j = 0; j < 4; j++) {
    int i = base + t * 4 + j;
    if (i < n) { off[i] = excl; cur[i] = excl; excl += v[j]; }
  }
}

// CSR placement: esx[pos] = x[src] (L1 row id), ess[pos] = src (L2 row id)
__global__ __launch_bounds__(256) void k_place2(const int* __restrict__ src,
    const int* __restrict__ dst, const int* __restrict__ et,
    const int* __restrict__ x, int* __restrict__ cur,
    int* __restrict__ esx, int* __restrict__ ess, int E, int N) {
  int e = blockIdx.x * 256 + threadIdx.x;
  if (e >= E) return;
  int s = src[e];
  int pos = atomicAdd(&cur[et[e] * N + dst[e]], 1);
  esx[pos] = x[s];
  ess[pos] = s;
}

// ---------------- relation aggregation, 8 ids per wave, MULTI-EDGE ONLY ---
// r23: ids with cnt==0 (37%, agg=0) and cnt==1 (37%, agg=source row, bit-
// identical since f2bf(bf2f(v)*1.0)==v) are no longer materialized — the
// GEMM gathers them directly (zero row / source row). Only cnt>=2 ids (26%)
// are accumulated and written: gather reads 153.6->~97MB, writes
// 153.6->~40MB per layer.
__global__ __launch_bounds__(256) void k_agg(const unsigned short* __restrict__ h,
    const int* __restrict__ rows, const int* __restrict__ off,
    unsigned short* __restrict__ out, int RN) {
  const int wave = threadIdx.x >> 6, lane = threadIdx.x & 63;
  const int base = (blockIdx.x * 4 + wave) * 8;
  if (base >= RN) return;

  int lo[8], hi[8];
#pragma unroll
  for (int j = 0; j < 8; j++) {
    int id = base + j;
    lo[j] = (id < RN) ? off[id] : 0;
    hi[j] = (id < RN) ? off[id + 1] : 0;
    if (hi[j] - lo[j] < 2) hi[j] = lo[j];   // skip: handled by GEMM gather
  }

  int r0[8];
#pragma unroll
  for (int j = 0; j < 8; j++)
    r0[j] = (hi[j] > lo[j]) ? rows[lo[j]] : 0;

  ushort4 v0[8];
#pragma unroll
  for (int j = 0; j < 8; j++)
    v0[j] = (hi[j] > lo[j])
        ? *(const ushort4*)(h + (size_t)r0[j] * D + lane * 4)
        : make_ushort4(0, 0, 0, 0);

  float a[8][4];
#pragma unroll
  for (int j = 0; j < 8; j++) {
    a[j][0] = bf2f(v0[j].x); a[j][1] = bf2f(v0[j].y);
    a[j][2] = bf2f(v0[j].z); a[j][3] = bf2f(v0[j].w);
  }

#pragma unroll
  for (int j = 0; j < 8; j++) {
    for (int p = lo[j] + 1; p < hi[j]; ++p) {
      int r = rows[p];
      ushort4 v = *(const ushort4*)(h + (size_t)r * D + lane * 4);
      a[j][0] += bf2f(v.x); a[j][1] += bf2f(v.y);
      a[j][2] += bf2f(v.z); a[j][3] += bf2f(v.w);
    }
  }

#pragma unroll
  for (int j = 0; j < 8; j++) {
    int id = base + j;
    if (id >= RN) continue;
    int c = hi[j] - lo[j];
    if (c < 2) continue;                    // not materialized
    float inv = 1.0f / (float)c;
    ushort4 o;
    o.x = f2bf(a[j][0] * inv); o.y = f2bf(a[j][1] * inv);
    o.z = f2bf(a[j][2] * inv); o.w = f2bf(a[j][3] * inv);
    *(ushort4*)(out + (size_t)id * D + lane * 4) = o;
  }
}

// ---------------- fused K=1024 bf16 MFMA GEMM, glds + BK=64 (r0 core) -----
// r23: r0's proven schedule (best measured: 86us, 3 blocks/CU; every hand-
// pipeline variant r18-r21 was equal or worse — latency hiding comes from
// occupancy, m114). ONE change: A-seg pointers for segs 1-3 are selected
// per row by CSR count (0 -> zero row; 1 -> direct source row, bit-exact;
// >=2 -> materialized agg row). Pure indirection swap on a0base — staging
// instruction stream identical to r0.
__global__ __launch_bounds__(512) void k_lgemm(
    const unsigned short* __restrict__ Aroot, const int* __restrict__ gidx,
    const unsigned short* agg, const int* __restrict__ rows_,
    const int* __restrict__ off_, const unsigned short* __restrict__ zrow,
    const unsigned short* __restrict__ wb,
    const float* __restrict__ bias, unsigned short* Cout, int M, int N) {
  __shared__ unsigned short AsU[2][128 * 32];    // 2 x 8 KB  [row][k]
  __shared__ unsigned short BsU[2][256 * 32];    // 2 x 16 KB [n][k]
  const int tid = threadIdx.x;
  const int w = tid >> 6, lane = tid & 63;
  const int wr = w >> 2, wc = w & 3;             // wave grid 2x4
  const int i0 = blockIdx.x * 128;
  const int ml = lane & 15, q = lane >> 4;

  // A staging: wave w stages rows w*16..w*16+15 (1 KB / instr).
  const int arow = w * 16 + (lane >> 2);
  const int achunk = lane & 3;
  int ra = i0 + arow;
  int rac = (ra < M) ? ra : (M - 1);
  const int rowA0 = gidx ? gidx[rac] : rac;
  const unsigned short* abase[4];
  abase[0] = Aroot + (size_t)rowA0 * D + achunk * 8;
#pragma unroll
  for (int r = 0; r < 3; r++) {
    int id = r * N + rac;
    int lo = off_[id];
    int cnt = off_[id + 1] - lo;
    const unsigned short* b;
    if (cnt == 0) b = zrow;                        // exact zeros
    else if (cnt == 1) b = Aroot + (size_t)rows_[lo] * D;  // mean of 1
    else b = agg + (size_t)id * D;                 // materialized
    abase[r + 1] = b + achunk * 8;
  }

  // B staging: wave w stages rows w*32..w*32+31 (2 instrs of 1 KB).
  const int brow = w * 32 + (lane >> 2);
  const int bchunk = lane & 3;
  const size_t bofs = (size_t)brow * D + bchunk * 8;

  floatx4 acc[4][4];
#pragma unroll
  for (int i = 0; i < 4; i++)
#pragma unroll
    for (int j = 0; j < 4; j++) acc[i][j] = (floatx4){0.f, 0.f, 0.f, 0.f};

  unsigned short* aldst[2] = {&AsU[0][w * 512], &AsU[1][w * 512]};
  unsigned short* bldst0[2] = {&BsU[0][w * 1024], &BsU[1][w * 1024]};
  unsigned short* bldst1[2] = {&BsU[0][w * 1024 + 512], &BsU[1][w * 1024 + 512]};

  for (int step = 0; step < 16; ++step) {
    __syncthreads();                    // previous step's LDS reads done
#pragma unroll
    for (int h = 0; h < 2; h++) {
      const int kabs = step * 64 + h * 32;
      const int seg = kabs >> 8, kloc = kabs & 255;
      glds16(abase[seg] + kloc, aldst[h]);
      const unsigned short* bb = wb + (size_t)seg * 65536 + bofs + kloc;
      glds16(bb, bldst0[h]);
      glds16(bb + 16 * D, bldst1[h]);
    }
    __syncthreads();                    // vmcnt drained -> LDS populated

#pragma unroll
    for (int h = 0; h < 2; h++) {
      short8 aF[4], bF[4];
#pragma unroll
      for (int mi = 0; mi < 4; mi++)
        aF[mi] = *(const short8*)&AsU[h][(wr * 64 + mi * 16 + ml) * 32 + q * 8];
#pragma unroll
      for (int ni = 0; ni < 4; ni++)
        bF[ni] = *(const short8*)&BsU[h][(wc * 64 + ni * 16 + ml) * 32 + q * 8];
#pragma unroll
      for (int mi = 0; mi < 4; mi++)
#pragma unroll
        for (int ni = 0; ni < 4; ni++)
          acc[mi][ni] = __builtin_amdgcn_mfma_f32_16x16x32_bf16(
              aF[mi], bF[ni], acc[mi][ni], 0, 0, 0);
    }
  }

  // per-block read-before-write over input pages: reads precede C writes
  __syncthreads();

  // epilogue: bias + ReLU + bf16; C/D layout col=lane&15, row=q*4+reg
  float bv[4];
#pragma unroll
  for (int ni = 0; ni < 4; ni++) bv[ni] = bias[wc * 64 + ni * 16 + ml];
#pragma unroll
  for (int mi = 0; mi < 4; mi++) {
#pragma unroll
    for (int ni = 0; ni < 4; ni++) {
      int col = wc * 64 + ni * 16 + ml;
#pragma unroll
      for (int j = 0; j < 4; j++) {
        int row = i0 + wr * 64 + mi * 16 + q * 4 + j;
        if (row < M) {
          float v = fmaxf(acc[mi][ni][j] + bv[ni], 0.f);
          Cout[(size_t)row * D + col] = f2bf(v);
        }
      }
    }
  }
}

// ---------------- fused graph mean-pool + linear head ----------------
__global__ __launch_bounds__(256) void k_poolfinal(
    const unsigned short* __restrict__ h, const int* __restrict__ gstart,
    const float* __restrict__ linW, const float* __restrict__ linb,
    float* __restrict__ out, int G) {
  __shared__ float red[4][D];
  __shared__ float sred[4][4];
  int g = blockIdx.x;
  int lo = gstart[g], hi = gstart[g + 1];
  int tid = threadIdx.x, wave = tid >> 6, lane = tid & 63;
  float a0 = 0.f, a1 = 0.f, a2 = 0.f, a3 = 0.f;
  for (int i = lo + wave; i < hi; i += 4) {
    ushort4 v = *(const ushort4*)(h + (size_t)i * D + lane * 4);
    a0 += bf2f(v.x); a1 += bf2f(v.y); a2 += bf2f(v.z); a3 += bf2f(v.w);
  }
  red[wave][lane * 4 + 0] = a0;
  red[wave][lane * 4 + 1] = a1;
  red[wave][lane * 4 + 2] = a2;
  red[wave][lane * 4 + 3] = a3;
  __syncthreads();
  float s = red[0][tid] + red[1][tid] + red[2][tid] + red[3][tid];
  float inv = (hi > lo) ? 1.0f / (float)(hi - lo) : 0.0f;
  float m = s * inv;                       // mean feature tid
  float4 wrow = *(const float4*)(linW + tid * 4);
  float p0 = m * wrow.x, p1 = m * wrow.y, p2 = m * wrow.z, p3 = m * wrow.w;
  for (int o = 32; o > 0; o >>= 1) {
    p0 += __shfl_down(p0, o, 64);
    p1 += __shfl_down(p1, o, 64);
    p2 += __shfl_down(p2, o, 64);
    p3 += __shfl_down(p3, o, 64);
  }
  if (lane == 0) {
    sred[wave][0] = p0; sred[wave][1] = p1;
    sred[wave][2] = p2; sred[wave][3] = p3;
  }
  __syncthreads();
  if (tid < 4)
    out[g * 4 + tid] = sred[0][tid] + sred[1][tid] + sred[2][tid] +
                       sred[3][tid] + linb[tid];
}

extern "C" void kernel_launch(void* const* d_in, const int* in_sizes, int n_in,
                              void* d_out, int out_size, void* d_ws, size_t ws_size,
                              hipStream_t stream) {
  const int*   x     = (const int*)d_in[0];
  const int*   ei    = (const int*)d_in[1];
  const int*   et    = (const int*)d_in[2];
  const int*   batch = (const int*)d_in[3];
  const float* table = (const float*)d_in[5];
  const float* W1    = (const float*)d_in[6];
  const float* root1 = (const float*)d_in[7];
  const float* b1    = (const float*)d_in[8];
  const float* W2    = (const float*)d_in[9];
  const float* root2 = (const float*)d_in[10];
  const float* b2    = (const float*)d_in[11];
  const float* linW  = (const float*)d_in[12];
  const float* linb  = (const float*)d_in[13];
  float* out = (float*)d_out;

  const int N = in_sizes[0];
  const int E = in_sizes[2];
  const int G = out_size / 4;
  const int VOC = in_sizes[5] / D;
  const int* src = ei;
  const int* dst = ei + E;
  const int RN = 3 * N;

  // ---- ws layout (~210 MB), page aliasing proven rounds 5-17 ----
  char* wsb = (char*)d_ws;
  size_t pg = (size_t)N * D * 2;
  unsigned short* P0 = (unsigned short*)wsb;
  unsigned short* P1 = (unsigned short*)(wsb + pg);
  unsigned short* P3 = (unsigned short*)(wsb + 3 * pg);
  unsigned short* wb = (unsigned short*)(wsb + 4 * pg);  // 2 layers x 4 mats
  unsigned short* zrow = wb + 2 * 4 * 65536;   // 256 shorts (512 B zero row)
  int*   off    = (int*)(zrow + 256);
  int*   esx    = off + (RN + 1);       // L1 row ids (= x[src])
  int*   ess    = esx + E;              // L2 row ids (= src)
  int*   gstart = ess + E;
  unsigned short* tableb = P3;          // alias (dead before L2 agg writes P3)
  int* cur  = (int*)P0;                 // alias (dead before L1 agg writes P0)
  int* bsum = cur + RN;                 // alias

  const int nb = (RN + SB - 1) / SB;

  // ---- setup: one fused kernel for all independent prep ----
  int nbZero = (RN + 1023) / 1024;
  int nbBounds = (N + 255) / 256;
  int nbCvt = (VOC * D + 255) / 256;
  int g0 = nbZero, g1 = g0 + nbBounds, g2 = g1 + nbCvt, g3 = g2 + 1024;
  k_setup<<<g3 + 1024, 256, 0, stream>>>(cur, RN, batch, gstart, N, G,
      table, tableb, VOC * D, root1, W1, root2, W2, wb, (int*)zrow,
      g0, g1, g2, g3);

  k_count_i<<<(E + 255) / 256, 256, 0, stream>>>(dst, et, cur, E, N);
  k_scan1<<<nb, 256, 0, stream>>>(cur, bsum, RN);
  k_scan2<<<1, 256, 0, stream>>>(bsum, nb, off + RN);
  k_scan3<<<nb, 256, 0, stream>>>(cur, bsum, off, cur, RN);
  k_place2<<<(E + 255) / 256, 256, 0, stream>>>(src, dst, et, x, cur, esx, ess, E, N);

  const int gagg = (RN + 31) / 32;      // 8 ids/wave x 4 waves
  const int ggemm = (N + 127) / 128;

  // ---- layer 1 ----
  k_agg<<<gagg, 256, 0, stream>>>(tableb, esx, off, P0, RN);
  k_lgemm<<<ggemm, 512, 0, stream>>>(tableb, x, P0, esx, off, zrow, wb, b1, P0, N, N);
  // ---- layer 2 ----
  k_agg<<<gagg, 256, 0, stream>>>(P0, ess, off, P1, RN);
  k_lgemm<<<ggemm, 512, 0, stream>>>(P0, nullptr, P1, ess, off, zrow,
                                     wb + 4 * 65536, b2, P1, N, N);

  // ---- pool + head fused ----
  k_poolfinal<<<G, 256, 0, stream>>>(P1, gstart, linW, linb, out, G);
}